// Round 4
// baseline (349.189 us; speedup 1.0000x reference)
//
#include <hip/hip_runtime.h>
#include <hip/hip_bf16.h>
#include <hip/hip_cooperative_groups.h>

namespace cg = cooperative_groups;

// Problem constants
#define B_   2
#define CH   32      // C
#define S_   1024    // H*W
#define DM   64      // D_MODEL
#define NH   4       // N_HEADS
#define DH   16      // D_HEAD
#define COUT 64
#define NJ   4       // j-split factor
#define L2E  1.44269504088896f

// ws layout (floats):
//   [512 .. 66047]    t_all[b][c][s]   (2*32*1024 transposed x)
//   [66048 ..]        num[n][h][jc][s] (64*4*4*1024 = 1048576 floats)
//   [+1048576]        den[n][h][jc][s]
#define WS_T   512
#define WS_P   66048
#define PSZ    1048576

#if __has_builtin(__builtin_amdgcn_exp2f)
#define EXP2F(x) __builtin_amdgcn_exp2f(x)
#else
#define EXP2F(x) exp2f(x)
#endif

// One fused cooperative kernel. 1024 blocks x 256 threads = 4 blocks/CU,
// all co-resident (VGPR ~64, LDS ~14 KB -> fits 4/CU easily).
// Phase P: every block redundantly computes qv/kv/vv -> a[4] in LDS (~48 fma/thread).
// Phase T: blocks 0..63 transpose x[b][s][c] -> t_all[b][c][s] in ws.
// grid.sync
// Phase A: block (n,sch,jc) computes partial num/den for 4 s-values/thread.
// grid.sync
// Phase F: blocks 0..127 combine j-partials, divide, merge over c, project ov.
__global__ __launch_bounds__(256, 4) void k_fused(const float* __restrict__ x,
                                                  const float* __restrict__ embed_w,
                                                  const float* __restrict__ q_w,
                                                  const float* __restrict__ k_w,
                                                  const float* __restrict__ v_w,
                                                  const float* __restrict__ o_w,
                                                  const float* __restrict__ merge_w,
                                                  float* __restrict__ ws,
                                                  float* __restrict__ out) {
    __shared__ __align__(16) float t[S_];          // 4 KB (phase A)
    __shared__ float sh[3 * 256];                  // 3 KB (phase P partials)
    __shared__ float em_s[DM];
    __shared__ float qv[DM], kv[DM], vv[DM];
    __shared__ float a_s[NH];
    __shared__ float tile[32][33];                 // 4.2 KB (phase T)
    __shared__ float part[4][4][16], W2[4][16], msh[32], ov_s[256];  // phase F

    cg::grid_group grid = cg::this_grid();
    const int bid = blockIdx.x;
    const int tid = threadIdx.x;

    // ---------------- Phase P: per-block prep (a[4], vv kept for F) ----------
    if (tid < DM) em_s[tid] = embed_w[tid];
    __syncthreads();
    {
        const int d = tid & 63, p = tid >> 6;
        float sq = 0.f, sk = 0.f, sv = 0.f;
        #pragma unroll
        for (int i = 0; i < 16; i++) {
            int e = p * 16 + i;
            float emv = em_s[e];
            sq = fmaf(q_w[d * DM + e], emv, sq);
            sk = fmaf(k_w[d * DM + e], emv, sk);
            sv = fmaf(v_w[d * DM + e], emv, sv);
        }
        sh[tid] = sq; sh[256 + tid] = sk; sh[512 + tid] = sv;
    }
    __syncthreads();
    if (tid < DM) {
        qv[tid] = ((sh[tid] + sh[64 + tid]) + (sh[128 + tid] + sh[192 + tid]));
        kv[tid] = ((sh[256 + tid] + sh[320 + tid]) + (sh[384 + tid] + sh[448 + tid]));
        vv[tid] = ((sh[512 + tid] + sh[576 + tid]) + (sh[640 + tid] + sh[704 + tid]));
    }
    __syncthreads();
    if (tid < NH) {
        float a = 0.f;
        #pragma unroll
        for (int i = 0; i < DH; i++) a = fmaf(qv[tid * DH + i], kv[tid * DH + i], a);
        a_s[tid] = a * 0.25f;   // 1/sqrt(16)
    }

    // ---------------- Phase T: blocks 0..63 transpose x -> t_all -------------
    if (bid < 64) {
        const int b  = bid >> 5;
        const int s0 = (bid & 31) * 32;
        const int c = tid & 31, r = tid >> 5;
        #pragma unroll
        for (int k = 0; k < 4; k++)
            tile[r + 8 * k][c] = x[(b * S_ + s0 + r + 8 * k) * CH + c];
        __syncthreads();
        const int sl = tid & 31, cr = tid >> 5;
        #pragma unroll
        for (int k = 0; k < 4; k++) {
            int c2 = cr + 8 * k;
            ws[WS_T + (b * CH + c2) * S_ + s0 + sl] = tile[sl][c2];
        }
    }

    grid.sync();

    // ---------------- Phase A: attention partials ----------------------------
    {
        const int n   = bid >> 4;
        const int sch = (bid >> 2) & 3;
        const int jc  = bid & 3;

        // coalesced stage of this channel's t row (4 KB)
        float4 v = ((const float4*)(ws + WS_T + n * S_))[tid];
        ((float4*)t)[tid] = v;
        float lmax = fmaxf(fmaxf(v.x, v.y), fmaxf(v.z, v.w));
        float lmin = fminf(fminf(v.x, v.y), fminf(v.z, v.w));
        #pragma unroll
        for (int off = 32; off; off >>= 1) {
            lmax = fmaxf(lmax, __shfl_xor(lmax, off));
            lmin = fminf(lmin, __shfl_xor(lmin, off));
        }
        __shared__ float redmax[4], redmin[4];
        if ((tid & 63) == 0) { redmax[tid >> 6] = lmax; redmin[tid >> 6] = lmin; }
        __syncthreads();
        const float tmax = fmaxf(fmaxf(redmax[0], redmax[1]), fmaxf(redmax[2], redmax[3]));
        const float tmin = fminf(fminf(redmin[0], redmin[1]), fminf(redmin[2], redmin[3]));

        const int h  = tid >> 6;
        const int sq = tid & 63;
        const float a = a_s[h];

        const float4 ts = ((const float4*)t)[sch * 64 + sq];
        float cc2[4], nm2[4], an[4], ad[4];
        const float tsv[4] = {ts.x, ts.y, ts.z, ts.w};
        #pragma unroll
        for (int i = 0; i < 4; i++) {
            float cc = tsv[i] * a;
            cc2[i] = cc * L2E;
            nm2[i] = -fmaxf(cc * tmax, cc * tmin) * L2E;   // exact logit max
            an[i] = 0.f; ad[i] = 0.f;
        }

        const float4* tj4 = ((const float4*)t) + jc * 64;
        #pragma unroll 2
        for (int jq = 0; jq < 64; jq++) {
            float4 tj = tj4[jq];                 // broadcast (same addr all lanes)
            const float tjv[4] = {tj.x, tj.y, tj.z, tj.w};
            #pragma unroll
            for (int k = 0; k < 4; k++) {
                #pragma unroll
                for (int i = 0; i < 4; i++) {
                    float e = EXP2F(fmaf(cc2[i], tjv[k], nm2[i]));
                    an[i] = fmaf(e, tjv[k], an[i]);
                    ad[i] += e;
                }
            }
        }

        const int base = (((n * NH + h) * NJ + jc) << 10) + sch * 256 + sq * 4;
        *(float4*)(ws + WS_P + base) = make_float4(an[0], an[1], an[2], an[3]);
        *(float4*)(ws + WS_P + PSZ + base) = make_float4(ad[0], ad[1], ad[2], ad[3]);
    }

    grid.sync();

    // ---------------- Phase F: blocks 0..127 finalize ------------------------
    if (bid >= 128) return;
    {
        // ov[o][h] from vv (still in LDS) + o_w
        const int o = tid & 63, hh0 = tid >> 6;
        float s = 0.f;
        #pragma unroll
        for (int i = 0; i < DH; i++)
            s = fmaf(o_w[o * DM + hh0 * DH + i], vv[hh0 * DH + i], s);
        ov_s[o * NH + hh0] = s;
        if (tid < 32) msh[tid] = merge_w[tid];
        __syncthreads();

        const int b  = bid >> 6;
        const int s0 = (bid & 63) * 16;
        const int sl = tid & 15, h = (tid >> 4) & 3, cg_ = tid >> 6;
        const float* pnum = ws + WS_P;
        const float* pden = ws + WS_P + PSZ;
        float acc = 0.f;
        #pragma unroll
        for (int k = 0; k < 8; k++) {
            int c = cg_ * 8 + k;
            int base = (((b * CH + c) * NH + h) * NJ) * S_ + s0 + sl;
            float ns = ((pnum[base] + pnum[base + 1024]) +
                        (pnum[base + 2048] + pnum[base + 3072]));
            float ds = ((pden[base] + pden[base + 1024]) +
                        (pden[base + 2048] + pden[base + 3072]));
            acc = fmaf(msh[c], ns * __builtin_amdgcn_rcpf(ds), acc);
        }
        part[cg_][h][sl] = acc;
        __syncthreads();
        if (tid < 64) {
            int hh = tid >> 4, ss = tid & 15;
            W2[hh][ss] = ((part[0][hh][ss] + part[1][hh][ss]) +
                          (part[2][hh][ss] + part[3][hh][ss]));
        }
        __syncthreads();
        #pragma unroll
        for (int rep = 0; rep < 4; rep++) {
            int idx = rep * 256 + tid;
            int o2 = idx & 63, ss = idx >> 6;
            float r = 0.f;
            #pragma unroll
            for (int hh = 0; hh < NH; hh++)
                r = fmaf(ov_s[o2 * NH + hh], W2[hh][ss], r);
            out[(b * S_ + s0 + ss) * COUT + o2] = r;
        }
    }
}

extern "C" void kernel_launch(void* const* d_in, const int* in_sizes, int n_in,
                              void* d_out, int out_size, void* d_ws, size_t ws_size,
                              hipStream_t stream) {
    const float* x       = (const float*)d_in[0];
    const float* embed_w = (const float*)d_in[1];
    const float* q_w     = (const float*)d_in[2];
    const float* k_w     = (const float*)d_in[3];
    const float* v_w     = (const float*)d_in[4];
    const float* o_w     = (const float*)d_in[5];
    const float* merge_w = (const float*)d_in[6];
    float* ws  = (float*)d_ws;
    float* out = (float*)d_out;

    void* args[] = {(void*)&x, (void*)&embed_w, (void*)&q_w, (void*)&k_w,
                    (void*)&v_w, (void*)&o_w, (void*)&merge_w,
                    (void*)&ws, (void*)&out};
    hipLaunchCooperativeKernel((const void*)k_fused, dim3(1024), dim3(256),
                               args, 0, stream);
}

// Round 5
// 108.067 us; speedup vs baseline: 3.2312x; 3.2312x over previous
//
#include <hip/hip_runtime.h>
#include <hip/hip_bf16.h>

// Problem constants
#define B_   2
#define CH   32      // C
#define S_   1024    // H*W
#define DM   64      // D_MODEL
#define NH   4       // N_HEADS
#define DH   16      // D_HEAD
#define COUT 64
#define L2E  1.44269504088896f

#if __has_builtin(__builtin_amdgcn_exp2f)
#define EXP2F(x) __builtin_amdgcn_exp2f(x)
#else
#define EXP2F(x) exp2f(x)
#endif

// ws layout (floats): [0 ..] w[n][h][s]  (64*4*1024 = 262144 floats, 1 MB)

// ---------------------------------------------------------------------------
// K1: 512 blocks = (n 0..63) x (sch 0..7); 256 threads = (h 4) x (sq 64).
// Per block: redundant prep of a[4]; gather channel row into LDS; min/max;
// each thread reduces ALL 1024 j for 2 s-values -> final w = num/den.
__global__ __launch_bounds__(256) void k_attn(const float* __restrict__ x,
                                              const float* __restrict__ embed_w,
                                              const float* __restrict__ q_w,
                                              const float* __restrict__ k_w,
                                              float* __restrict__ w_out) {
    __shared__ __align__(16) float t[S_];
    __shared__ float sh[2 * 256];
    __shared__ float em_s[DM];
    __shared__ float a_s[NH];
    __shared__ float redmax[4], redmin[4];

    const int bid = blockIdx.x;
    const int tid = threadIdx.x;
    const int n = bid >> 3, sch = bid & 7;
    const int b = n >> 5, c = n & 31;

    // --- prep: a[h] = (qv.kv)|head_h / sqrt(DH), recomputed per block ---
    if (tid < DM) em_s[tid] = embed_w[tid];
    __syncthreads();
    {
        const int d = tid & 63, p = tid >> 6;
        float sq_ = 0.f, sk_ = 0.f;
        #pragma unroll
        for (int i = 0; i < 16; i++) {
            int e = p * 16 + i;
            float emv = em_s[e];
            sq_ = fmaf(q_w[d * DM + e], emv, sq_);
            sk_ = fmaf(k_w[d * DM + e], emv, sk_);
        }
        sh[tid] = sq_; sh[256 + tid] = sk_;
    }
    // --- stage channel row: t[s] = x[b, s, c], strided gather (L2-resident) ---
    const float* xp = x + b * (S_ * CH) + c;
    float4 mv;
    {
        float v0 = xp[(tid * 4 + 0) * CH];
        float v1 = xp[(tid * 4 + 1) * CH];
        float v2 = xp[(tid * 4 + 2) * CH];
        float v3 = xp[(tid * 4 + 3) * CH];
        mv = make_float4(v0, v1, v2, v3);
        ((float4*)t)[tid] = mv;
    }
    __syncthreads();   // sh complete
    if (tid < NH) {
        float a = 0.f;
        #pragma unroll
        for (int i = 0; i < DH; i++) {
            int d = tid * DH + i;
            float qv = (sh[d] + sh[64 + d]) + (sh[128 + d] + sh[192 + d]);
            float kv = (sh[256 + d] + sh[320 + d]) + (sh[384 + d] + sh[448 + d]);
            a = fmaf(qv, kv, a);
        }
        a_s[tid] = a * 0.25f;   // 1/sqrt(16)
    }
    float lmax = fmaxf(fmaxf(mv.x, mv.y), fmaxf(mv.z, mv.w));
    float lmin = fminf(fminf(mv.x, mv.y), fminf(mv.z, mv.w));
    #pragma unroll
    for (int off = 32; off; off >>= 1) {
        lmax = fmaxf(lmax, __shfl_xor(lmax, off));
        lmin = fminf(lmin, __shfl_xor(lmin, off));
    }
    if ((tid & 63) == 0) { redmax[tid >> 6] = lmax; redmin[tid >> 6] = lmin; }
    __syncthreads();   // t, a_s, redmax/min all complete
    const float tmax = fmaxf(fmaxf(redmax[0], redmax[1]), fmaxf(redmax[2], redmax[3]));
    const float tmin = fminf(fminf(redmin[0], redmin[1]), fminf(redmin[2], redmin[3]));

    const int h = tid >> 6, sq = tid & 63;
    const float a = a_s[h];
    const int s0 = sch * 128 + sq;
    const float ts0 = t[s0], ts1 = t[s0 + 64];

    const float cc0 = ts0 * a,        cc1 = ts1 * a;
    const float cc20 = cc0 * L2E,     cc21 = cc1 * L2E;
    const float nm20 = -fmaxf(cc0 * tmax, cc0 * tmin) * L2E;  // exact logit max
    const float nm21 = -fmaxf(cc1 * tmax, cc1 * tmin) * L2E;
    float an0 = 0.f, ad0 = 0.f, an1 = 0.f, ad1 = 0.f;

    const float4* t4 = (const float4*)t;
    #pragma unroll 2
    for (int jq = 0; jq < 256; jq++) {
        float4 tj = t4[jq];                       // broadcast, conflict-free
        const float tjv[4] = {tj.x, tj.y, tj.z, tj.w};
        #pragma unroll
        for (int k = 0; k < 4; k++) {
            float e0 = EXP2F(fmaf(cc20, tjv[k], nm20));
            float e1 = EXP2F(fmaf(cc21, tjv[k], nm21));
            an0 = fmaf(e0, tjv[k], an0); ad0 += e0;
            an1 = fmaf(e1, tjv[k], an1); ad1 += e1;
        }
    }
    w_out[(n * NH + h) * S_ + s0]      = an0 / ad0;
    w_out[(n * NH + h) * S_ + s0 + 64] = an1 / ad1;
}

// ---------------------------------------------------------------------------
// K2: 128 blocks = (b 2) x (s-tile 64 of 16); 256 threads.
// Redundant prep of vv -> ov[64][4]; then W2[h][s] = sum_c merge[c]*w, and
// out[b,s,o] = sum_h ov[o][h]*W2[h][s].
__global__ __launch_bounds__(256) void k_fin(const float* __restrict__ w_arr,
                                             const float* __restrict__ embed_w,
                                             const float* __restrict__ v_w,
                                             const float* __restrict__ o_w,
                                             const float* __restrict__ merge_w,
                                             float* __restrict__ out) {
    __shared__ float em_s[DM];
    __shared__ float sh[256];
    __shared__ float vv[DM];
    __shared__ float ov_s[256];
    __shared__ float part[4][4][16];
    __shared__ float W2[4][16];
    __shared__ float msh[32];
    const int bid = blockIdx.x, tid = threadIdx.x;

    if (tid < DM) em_s[tid] = embed_w[tid];
    __syncthreads();
    {
        const int d = tid & 63, p = tid >> 6;
        float sv = 0.f;
        #pragma unroll
        for (int i = 0; i < 16; i++) {
            int e = p * 16 + i;
            sv = fmaf(v_w[d * DM + e], em_s[e], sv);
        }
        sh[tid] = sv;
    }
    __syncthreads();
    if (tid < DM) vv[tid] = (sh[tid] + sh[64 + tid]) + (sh[128 + tid] + sh[192 + tid]);
    if (tid < 32) msh[tid] = merge_w[tid];
    __syncthreads();
    {
        const int o = tid & 63, hh0 = tid >> 6;
        float s = 0.f;
        #pragma unroll
        for (int i = 0; i < DH; i++)
            s = fmaf(o_w[o * DM + hh0 * DH + i], vv[hh0 * DH + i], s);
        ov_s[o * NH + hh0] = s;
    }

    const int b  = bid >> 6;
    const int s0 = (bid & 63) * 16;
    const int sl = tid & 15, h = (tid >> 4) & 3, cg_ = tid >> 6;
    float acc = 0.f;
    #pragma unroll
    for (int k = 0; k < 8; k++) {
        int c = cg_ * 8 + k;
        acc = fmaf(msh[c], w_arr[((b * CH + c) * NH + h) * S_ + s0 + sl], acc);
    }
    part[cg_][h][sl] = acc;
    __syncthreads();   // ov_s and part complete
    if (tid < 64) {
        int hh = tid >> 4, ss = tid & 15;
        W2[hh][ss] = (part[0][hh][ss] + part[1][hh][ss]) +
                     (part[2][hh][ss] + part[3][hh][ss]);
    }
    __syncthreads();
    #pragma unroll
    for (int rep = 0; rep < 4; rep++) {
        int idx = rep * 256 + tid;
        int o2 = idx & 63, ss = idx >> 6;
        float r = 0.f;
        #pragma unroll
        for (int hh = 0; hh < NH; hh++)
            r = fmaf(ov_s[o2 * NH + hh], W2[hh][ss], r);
        out[(b * S_ + s0 + ss) * COUT + o2] = r;
    }
}

extern "C" void kernel_launch(void* const* d_in, const int* in_sizes, int n_in,
                              void* d_out, int out_size, void* d_ws, size_t ws_size,
                              hipStream_t stream) {
    const float* x       = (const float*)d_in[0];
    const float* embed_w = (const float*)d_in[1];
    const float* q_w     = (const float*)d_in[2];
    const float* k_w     = (const float*)d_in[3];
    const float* v_w     = (const float*)d_in[4];
    const float* o_w     = (const float*)d_in[5];
    const float* merge_w = (const float*)d_in[6];
    float* ws  = (float*)d_ws;
    float* out = (float*)d_out;

    k_attn<<<512, 256, 0, stream>>>(x, embed_w, q_w, k_w, ws);
    k_fin<<<B_ * 64, 256, 0, stream>>>(ws, embed_w, v_w, o_w, merge_w, out);
}